// Round 6
// baseline (389.629 us; speedup 1.0000x reference)
//
#include <hip/hip_runtime.h>
#include <hip/hip_bf16.h>

#define Bb 128
#define LQ 32
#define LD 512
#define Hh 768
#define Cc 128

#define DBLOCKS ((Bb * LD) / 64)   // 1024 doc blocks (64 rows each)
#define QBLOCKS ((Bb * LQ) / 64)   // 64 query blocks

typedef short bf16x8 __attribute__((ext_vector_type(8)));
typedef float f32x4 __attribute__((ext_vector_type(4)));

__device__ __forceinline__ short f2bf(float f) {
  union { float f; unsigned u; } v;
  v.f = f;
  unsigned u = v.u + (0x7FFFu + ((v.u >> 16) & 1u));  // RNE
  return (short)(u >> 16);
}

__device__ __forceinline__ void pack8(bf16x8& d, const float4& lo, const float4& hi) {
  d[0] = f2bf(lo.x); d[1] = f2bf(lo.y); d[2] = f2bf(lo.z); d[3] = f2bf(lo.w);
  d[4] = f2bf(hi.x); d[5] = f2bf(hi.y); d[6] = f2bf(hi.z); d[7] = f2bf(hi.w);
}

// K0: W (H,C) fp32 -> Wt (C,H) bf16 (transposed so B-fragments are contiguous)
__global__ __launch_bounds__(256) void k_wt(const float* __restrict__ W,
                                            short* __restrict__ Wt) {
  int idx = blockIdx.x * 256 + threadIdx.x;  // grid covers H*C exactly
  int h = idx >> 7;   // / 128
  int c = idx & 127;
  Wt[c * Hh + h] = f2bf(W[idx]);
}

// Merged projection GEMM (query+doc): Y = X @ W + b_comp, fused mask
// (+ importance relu-dot for docs).
// NO LDS, NO barriers: waves free-run like a copy kernel (R3/R4/R5 showed
// every barrier-phased LDS pipeline caps at ~12.7 GB/s/CU, half of copy).
// Wave tile 16 rows x 128 cols; A rows are wave-private, fragments loaded
// straight from global (16 rows x 128 B = full 64-B segments); B fragments
// from L2-hot Wt (16 rows x 64 B, full segments). Next-chunk A-loads issue
// BEFORE this chunk's pack-wait so they stay in flight (in-order vmcnt:
// waiting on older A never retires them).
__global__ __launch_bounds__(256, 4) void k_proj_all(
    const float* __restrict__ qh, const float* __restrict__ dh,
    const short* __restrict__ Wt, const float* __restrict__ bcomp,
    const int* __restrict__ qmask, const int* __restrict__ dmask,
    const float* __restrict__ wstop, const float* __restrict__ bstop,
    float* __restrict__ qv, float* __restrict__ dv) {
  const int tid = threadIdx.x;
  const int w = tid >> 6;
  const int lane = tid & 63;
  const int quad = lane >> 4;
  const int lm = lane & 15;

  const int blk = blockIdx.x;
  const bool is_doc = blk < DBLOCKS;
  const float* X;
  float* Y;
  const int* mask;
  long row0;
  if (is_doc) {
    X = dh; Y = dv; mask = dmask;
    row0 = (long)blk * 64 + w * 16;
  } else {
    X = qh; Y = qv; mask = qmask;
    row0 = (long)(blk - DBLOCKS) * 64 + w * 16;
  }

  // A fragment source: lane (lm,quad) reads row row0+lm, k = quad*8 + [0,8)
  // within each 32-k step -> two float4 per step, four per 64-k chunk.
  const float* pa = X + (row0 + lm) * (long)Hh + quad * 8;
  // B fragment source: Wt[n][k], n = j*16+lm, k = quad*8 + [0,8) per step.
  const short* pb = Wt + lm * Hh + quad * 8;

  f32x4 acc[8];
#pragma unroll
  for (int j = 0; j < 8; ++j) acc[j] = (f32x4){0.f, 0.f, 0.f, 0.f};

  // Preload chunk 0's A.
  float4 a0 = *(const float4*)(pa);
  float4 a1 = *(const float4*)(pa + 4);
  float4 a2 = *(const float4*)(pa + 32);
  float4 a3 = *(const float4*)(pa + 36);

#pragma unroll 1
  for (int kk = 0; kk < Hh; kk += 64) {
    // Issue next chunk's A-loads FIRST; they ride out this whole iteration.
    const int kn = (kk + 64 < Hh) ? kk + 64 : 0;
    float4 n0 = *(const float4*)(pa + kn);
    float4 n1 = *(const float4*)(pa + kn + 4);
    float4 n2 = *(const float4*)(pa + kn + 32);
    float4 n3 = *(const float4*)(pa + kn + 36);

    // ks = 0 half: pack waits only on the OLDER a0..a3 (issued last iter);
    // n0..n3 remain outstanding.
    bf16x8 fa;
    pack8(fa, a0, a1);
#pragma unroll
    for (int j = 0; j < 8; ++j) {
      bf16x8 fb = *(const bf16x8*)(pb + j * 16 * Hh + kk);
      acc[j] = __builtin_amdgcn_mfma_f32_16x16x32_bf16(fa, fb, acc[j], 0, 0, 0);
    }
    // ks = 1 half.
    pack8(fa, a2, a3);
#pragma unroll
    for (int j = 0; j < 8; ++j) {
      bf16x8 fb = *(const bf16x8*)(pb + j * 16 * Hh + kk + 32);
      acc[j] = __builtin_amdgcn_mfma_f32_16x16x32_bf16(fa, fb, acc[j], 0, 0, 0);
    }
    a0 = n0; a1 = n1; a2 = n2; a3 = n3;
  }

  // Epilogue. C/D layout: col = j*16 + lm, row = quad*4 + r (within wave tile).
  float bc[8], wsv[8];
#pragma unroll
  for (int j = 0; j < 8; ++j) bc[j] = bcomp[j * 16 + lm];
  if (is_doc) {
#pragma unroll
    for (int j = 0; j < 8; ++j) wsv[j] = wstop[j * 16 + lm];
  }
  const float bs = is_doc ? bstop[0] : 0.f;

#pragma unroll
  for (int r = 0; r < 4; ++r) {
    const long row = row0 + quad * 4 + r;
    float v[8];
#pragma unroll
    for (int j = 0; j < 8; ++j) v[j] = acc[j][r] + bc[j];
    float scale;
    if (is_doc) {
      // importance = relu(d_tok . w_stop + b_stop); the row's 128 cols live
      // on the 16 lanes of this quad -> butterfly sum within the quad.
      float p = 0.f;
#pragma unroll
      for (int j = 0; j < 8; ++j) p += v[j] * wsv[j];
      p += __shfl_xor(p, 1);
      p += __shfl_xor(p, 2);
      p += __shfl_xor(p, 4);
      p += __shfl_xor(p, 8);
      float imp = fmaxf(p + bs, 0.f);
      scale = imp * (float)mask[row];
    } else {
      scale = (float)mask[row];
    }
    float* yr = Y + row * Cc;
#pragma unroll
    for (int j = 0; j < 8; ++j) yr[j * 16 + lm] = v[j] * scale;
  }
}

// Scores: per (chunk of 64 doc tokens, batch): partial max over k per q row.
__global__ __launch_bounds__(256) void k_scores(
    const float* __restrict__ Qv, const float* __restrict__ Dv,
    const int* __restrict__ dmask, float* __restrict__ partial) {
  const int chunk = blockIdx.x;  // 0..7
  const int b = blockIdx.y;
  const int tid = threadIdx.x;
  __shared__ float lq[LQ][Cc + 4];   // +4 keeps 16B align, breaks conflicts
  __shared__ float ldv[64][Cc + 4];
  __shared__ float pm[LQ][16];
  __shared__ int dmsk[64];

  {
    const float4* src = (const float4*)(Qv + (size_t)b * LQ * Cc);
    for (int i = tid; i < LQ * Cc / 4; i += 256) {
      float4 v = src[i];
      int q = i >> 5;
      int c = (i & 31) << 2;
      *(float4*)&lq[q][c] = v;
    }
  }
  const int k0 = chunk * 64;
  {
    const float4* src = (const float4*)(Dv + ((size_t)b * LD + k0) * Cc);
    for (int i = tid; i < 64 * Cc / 4; i += 256) {
      float4 v = src[i];
      int k = i >> 5;
      int c = (i & 31) << 2;
      *(float4*)&ldv[k][c] = v;
    }
  }
  if (tid < 64) dmsk[tid] = dmask[(size_t)b * LD + k0 + tid];
  __syncthreads();

  const int qt = tid & 15;   // q rows qt and qt+16
  const int kt = tid >> 4;   // 4 doc tokens kt*4..+3
  const int kbase = kt * 4;
  float a[2][4];
#pragma unroll
  for (int qi = 0; qi < 2; ++qi)
#pragma unroll
    for (int ki = 0; ki < 4; ++ki) a[qi][ki] = 0.f;

  for (int c = 0; c < Cc; c += 4) {
    float4 q0 = *(float4*)&lq[qt][c];
    float4 q1 = *(float4*)&lq[qt + 16][c];
    float4 d0 = *(float4*)&ldv[kbase + 0][c];
    float4 d1 = *(float4*)&ldv[kbase + 1][c];
    float4 d2 = *(float4*)&ldv[kbase + 2][c];
    float4 d3 = *(float4*)&ldv[kbase + 3][c];
    a[0][0] += q0.x * d0.x + q0.y * d0.y + q0.z * d0.z + q0.w * d0.w;
    a[0][1] += q0.x * d1.x + q0.y * d1.y + q0.z * d1.z + q0.w * d1.w;
    a[0][2] += q0.x * d2.x + q0.y * d2.y + q0.z * d2.z + q0.w * d2.w;
    a[0][3] += q0.x * d3.x + q0.y * d3.y + q0.z * d3.z + q0.w * d3.w;
    a[1][0] += q1.x * d0.x + q1.y * d0.y + q1.z * d0.z + q1.w * d0.w;
    a[1][1] += q1.x * d1.x + q1.y * d1.y + q1.z * d1.z + q1.w * d1.w;
    a[1][2] += q1.x * d2.x + q1.y * d2.y + q1.z * d2.z + q1.w * d2.w;
    a[1][3] += q1.x * d3.x + q1.y * d3.y + q1.z * d3.z + q1.w * d3.w;
  }
  float m0 = -1000.f, m1 = -1000.f;
#pragma unroll
  for (int ki = 0; ki < 4; ++ki) {
    if (dmsk[kbase + ki]) {
      m0 = fmaxf(m0, a[0][ki]);
      m1 = fmaxf(m1, a[1][ki]);
    }
  }
  pm[qt][kt] = m0;
  pm[qt + 16][kt] = m1;
  __syncthreads();
  if (tid < LQ) {
    float mx = pm[tid][0];
#pragma unroll
    for (int t = 1; t < 16; ++t) mx = fmaxf(mx, pm[tid][t]);
    partial[((size_t)b * LQ + tid) * 8 + chunk] = mx;
  }
}

// Finalize: cls dot on raw CLS vectors, max over chunks, masked sum, merge.
__global__ __launch_bounds__(256) void k_final(
    const float* __restrict__ qh, const float* __restrict__ dh,
    const int* __restrict__ qmask, const float* __restrict__ partial,
    const float* __restrict__ merger, float* __restrict__ out) {
  const int b = blockIdx.x;
  const int tid = threadIdx.x;
  __shared__ float red[256];
  __shared__ float clss;
  const float* qc = qh + (size_t)b * LQ * Hh;  // q row 0 = CLS
  const float* dc = dh + (size_t)b * LD * Hh;  // d row 0 = CLS
  float s = 0.f;
  for (int h = tid; h < Hh; h += 256) s += qc[h] * dc[h];
  red[tid] = s;
  __syncthreads();
  for (int off = 128; off > 0; off >>= 1) {
    if (tid < off) red[tid] += red[tid + off];
    __syncthreads();
  }
  if (tid == 0) clss = red[0];
  __syncthreads();
  float t = 0.f;
  if (tid < LQ) {
    const float* pp = partial + ((size_t)b * LQ + tid) * 8;
    float mx = pp[0];
#pragma unroll
    for (int c = 1; c < 8; ++c) mx = fmaxf(mx, pp[c]);
    if (qmask[b * LQ + tid]) t = mx;
  }
  red[tid] = t;
  __syncthreads();
  for (int off = 128; off > 0; off >>= 1) {
    if (tid < off) red[tid] += red[tid + off];
    __syncthreads();
  }
  if (tid == 0) {
    float w = 1.f / (1.f + expf(-merger[0]));
    float cs = clss * w;
    float ts = red[0] * (1.f - w);
    out[b] = cs + ts;        // score
    out[Bb + b] = cs;        // cls_score
    out[2 * Bb + b] = ts;    // term_score
  }
}

extern "C" void kernel_launch(void* const* d_in, const int* in_sizes, int n_in,
                              void* d_out, int out_size, void* d_ws, size_t ws_size,
                              hipStream_t stream) {
  const float* qh  = (const float*)d_in[0];  // (B,LQ,H)
  const float* dh  = (const float*)d_in[1];  // (B,LD,H)
  const int*   qm  = (const int*)d_in[2];    // (B,LQ)
  const int*   dm  = (const int*)d_in[3];    // (B,LD)
  const float* W   = (const float*)d_in[4];  // (H,C)
  const float* bc  = (const float*)d_in[5];  // (C)
  const float* wst = (const float*)d_in[6];  // (C,1)
  const float* bst = (const float*)d_in[7];  // (1)
  const float* mrg = (const float*)d_in[8];  // (1)
  float* out = (float*)d_out;                // 3*B floats

  char* ws = (char*)d_ws;
  short* Wt  = (short*)ws;                                  // 192 KB bf16 W^T
  float* qv  = (float*)(ws + 196608);                       // 2 MB q_vecs
  float* dv  = (float*)(ws + 196608 + 2097152);             // 32 MB d_vecs
  float* prt = (float*)(ws + 196608 + 2097152 + 33554432);  // 128 KB partial max

  k_wt<<<(Hh * Cc) / 256, 256, 0, stream>>>(W, Wt);
  k_proj_all<<<DBLOCKS + QBLOCKS, 256, 0, stream>>>(qh, dh, Wt, bc, qm, dm,
                                                    wst, bst, qv, dv);
  k_scores<<<dim3(8, Bb), 256, 0, stream>>>(qv, dv, dm, prt);
  k_final<<<Bb, 256, 0, stream>>>(qh, dh, qm, prt, mrg, out);
}